// Round 4
// baseline (356.512 us; speedup 1.0000x reference)
//
#include <hip/hip_runtime.h>
#include <stdint.h>

typedef unsigned short u16;
typedef __attribute__((ext_vector_type(8))) __bf16 bf16x8;
typedef __attribute__((ext_vector_type(4))) float f32x4;

__device__ __forceinline__ u16 f2bf(float f) {
    union { float f; uint32_t u; } v; v.f = f;
    uint32_t r = (v.u + 0x7FFFu + ((v.u >> 16) & 1u)) >> 16;
    return (u16)r;
}

__device__ __forceinline__ void lds_fence() {
    __asm__ volatile("s_waitcnt lgkmcnt(0)" ::: "memory");
}

#define BAR()   __asm__ volatile("s_barrier" ::: "memory")
#define VMW(N)  __asm__ volatile("s_waitcnt vmcnt(" #N ")" ::: "memory")
#define SCHB()  __builtin_amdgcn_sched_barrier(0)

// ---------------------------------------------------------------------------
// ROUND 4: LDS-BW-bound diagnosis (4000 cy/Kt ≈ 256 KB LDS traffic @64 B/cy,
// schedule-invariant across rounds 1-3). Fix = remove B from LDS entirely:
// B-fragments go global(L2)->VGPR via inline-asm global_load_dwordx4 in MFMA
// layout (lane = 16 rows x 16B, 4 lanes/64B line). A stays LDS-staged
// (global_load_lds, XOR-swizzled source, linear dest). LDS traffic/Kt drops
// 256 KB -> 80 KB (A reads 64 + stage writes 16) ~= MFMA 1242 cy.
//
// Uniform geometry, all modes: BM=128, BN=256, 512 thr (8 waves 2M x 4N),
// per-wave 64x64, acc[4][4]. Grids are exact multiples of 256 CUs:
//   m0: 64 bm x 12 bn           = 768 (3/CU even; fixes the 1.5-round tail)
//   m2: 16 bm x 8 bn x 4 z      = 512 (2/CU even)
//   m3: 16 bm x 4 bn x 4 z      = 256 (1/CU even; fixes skinny-BN LDS-bound)
//
// K-loop: 1 barrier per K-tile. Phase t = { sched_barrier | ds_read fa[4][2]
// (buf t&1) | 32 MFMA (fb slot t&1) | 8 asm B-gathers (tile t+2, slot t&1) |
// 2 A-stage chunks (tile t+2, buf t&1) | vmcnt(10) | s_barrier }.
// FIFO ledger (verified, incl. prologue): outstanding at VMW = 20
// [B(t+1)x8, A(t+1)x2, B(t+2)x8, A(t+2)x2]; VMW(10) retires B(t+1),A(t+1) =
// exactly what the next phase reads, issued one full phase earlier. Cross-wave
// A visibility: every wave passes VMW before BAR; reads are post-BAR. WAR on
// buf(t&1): this phase's own fa reads complete ~120cy; the overwriting stage
// write lands >=200cy after issuing post-MFMA (>=600cy after reads). B regs
// are SSA (asm "=&v" outputs) - no reg WAR hazard. Tail wraps mod NT
// (stale-safe); gathers past K-end read adjacent ws memory (harmless).
// Rule #18: sched_barrier(0) after each BAR so MFMA can't hoist above the
// vmcnt that guarantees its asm-produced B operands.
//
// MODE 0: fused QKV, N=3072. bn>>2: 0->q(o0,b0), 1->k(o1,b1), 2->v(b2)
//         transposed [b,e,s] into o2.
// MODE 2: exp(s*scale) bf16 into o0 + atomic row sums into lsum.
// MODE 3: fp32 out = acc / lsum[row] into o3.
// ---------------------------------------------------------------------------
template<int MODE>
__global__ __launch_bounds__(512, 2) void gemm8(
    const u16* __restrict__ A, const u16* __restrict__ Bt,
    const float* __restrict__ b0, const float* __restrict__ b1, const float* __restrict__ b2,
    u16* __restrict__ o0, u16* __restrict__ o1, u16* __restrict__ o2,
    float* __restrict__ o3, float* __restrict__ lsum,
    int M, int N, int K, long sA, long sB, long sC, float scale)
{
    extern __shared__ __align__(16) u16 smem[];

    const int t = threadIdx.x;
    const int lane = t & 63;
    const int wave = t >> 6;
    const int wm = wave >> 2;   // 0..1  (64-row half)
    const int wn = wave & 3;    // 0..3  (64-col strip)

    // ---- XCD-clustered grid decode (xcd = id&7 HW round-robin) ----
    const int id = blockIdx.x;
    const int xcd = id & 7;
    const int s = id >> 3;
    int bm, bn;
    long bz;
    if (MODE == 0) {            // 768: XCD owns a 1024-row A band (L2-resident)
        bm = xcd * 8 + (s & 7); // 0..63
        bn = s >> 3;            // 0..11, bn-major within XCD -> B strip reuse
        bz = 0;
    } else if (MODE == 2) {     // 512
        bz = xcd >> 1;
        bm = (xcd & 1) * 8 + (s & 7); // 0..15
        bn = s >> 3;                  // 0..7
    } else {                    // 256
        bz = xcd >> 1;
        bm = (xcd & 1) * 8 + (s & 7); // 0..15
        bn = s >> 3;                  // 0..3
    }
    const int row0 = bm * 128;
    const int col0 = bn * 256;

    const u16* Ab = A + bz * sA;
    const u16* Bb = Bt + bz * sB;

    f32x4 acc[4][4];
#pragma unroll
    for (int i = 0; i < 4; ++i)
#pragma unroll
        for (int j = 0; j < 4; ++j)
            acc[i][j] = (f32x4){0.f, 0.f, 0.f, 0.f};

    // ---- A staging (inverse-swizzled global source, linear LDS dest) ----
    const int trow = t >> 2;                             // 0..127
    const int gcol = ((t & 3) * 8) ^ ((trow & 8) << 1);
    const u16* aRow = Ab + (long)(row0 + trow) * K + gcol;

    auto stageA = [&](int buf, int kt, int kb) {
        const u16* g = aRow + kt * 64 + kb * 32;
        u16* d = smem + buf * 8192 + kb * 4096 + t * 8;
        __builtin_amdgcn_global_load_lds(
            (const __attribute__((address_space(1))) void*)g,
            (__attribute__((address_space(3))) void*)d, 16, 0, 0);
    };

    // ---- fragment addressing ----
    const int fm = lane & 15;
    const int fk = (lane >> 4) * 8;
    const int fcol = fk ^ ((fm & 8) << 1);               // LDS swizzle (A only)
    const int aB = (wm * 64 + fm) * 32 + fcol;           // + kh*4096 + mi*512

    // ---- B base pointers (MFMA B-layout gather; no LDS, no swizzle) ----
    const u16* bp[4];
#pragma unroll
    for (int ni = 0; ni < 4; ++ni)
        bp[ni] = Bb + (long)(col0 + wn * 64 + ni * 16 + fm) * K + fk;

    f32x4 fbE[4][2], fbO[4][2];   // B reg double-buffer: even/odd K-tiles

#define GATHER(FB) do { \
    _Pragma("unroll") for (int ni = 0; ni < 4; ++ni) { \
        asm volatile("global_load_dwordx4 %0, %2, off\n\t" \
                     "global_load_dwordx4 %1, %2, off offset:64" \
            : "=&v"(FB[ni][0]), "=&v"(FB[ni][1]) : "v"(bp[ni]) : "memory"); \
    } \
    _Pragma("unroll") for (int ni = 0; ni < 4; ++ni) bp[ni] += 64; \
} while (0)

#define PHASE(BUF, FB, T2) do { \
    SCHB(); \
    bf16x8 fa[4][2]; \
    _Pragma("unroll") for (int mi = 0; mi < 4; ++mi) \
    _Pragma("unroll") for (int kh = 0; kh < 2; ++kh) \
        fa[mi][kh] = *(const bf16x8*)&smem[(BUF) * 8192 + kh * 4096 + aB + mi * 512]; \
    __builtin_amdgcn_s_setprio(1); \
    _Pragma("unroll") for (int mi = 0; mi < 4; ++mi) \
    _Pragma("unroll") for (int ni = 0; ni < 4; ++ni) \
    _Pragma("unroll") for (int kh = 0; kh < 2; ++kh) \
        acc[mi][ni] = __builtin_amdgcn_mfma_f32_16x16x32_bf16( \
            fa[mi][kh], __builtin_bit_cast(bf16x8, FB[ni][kh]), acc[mi][ni], 0, 0, 0); \
    __builtin_amdgcn_s_setprio(0); \
    GATHER(FB); \
    stageA(BUF, (T2), 0); stageA(BUF, (T2), 1); \
    VMW(10); \
    BAR(); \
} while (0)

    const int NT = K >> 6;
    const int NI = NT >> 1;

    // ---- prologue: B(0)->fbE, A(0)->buf0, B(1)->fbO, A(1)->buf1 ----
    GATHER(fbE);
    stageA(0, 0, 0); stageA(0, 0, 1);
    GATHER(fbO);
    stageA(1, 1, 0); stageA(1, 1, 1);
    VMW(10);   // retire B(0)+A(0)
    BAR();

    for (int i = 0; i < NI; ++i) {
        int t2 = 2 * i + 2; if (t2 >= NT) t2 -= NT;
        int t3 = 2 * i + 3; if (t3 >= NT) t3 -= NT;
        PHASE(0, fbE, t2);
        PHASE(1, fbO, t3);
    }

    // ---- drain stale in-flight stagers before LDS reuse ----
    VMW(0);
    BAR();

    // C/D layout: col = lane&15, row = (lane>>4)*4 + reg
    const int cm = (lane >> 4) * 4;
    const int cn = lane & 15;
    u16* Ew = smem + wave * 8192;      // 16 KiB per-wave window
    const int row0w = row0 + wm * 64;
    const int col0w = col0 + wn * 64;

    if constexpr (MODE == 3) {
        // ---- fp32 out (PV), /lsum[row]: 2 passes of 32 rows x 64 cols ----
        float* Fw = (float*)Ew;        // 32*68*4 = 8704 B <= 16384
#pragma unroll
        for (int p = 0; p < 2; ++p) {
            if (p) lds_fence();
#pragma unroll
            for (int m2 = 0; m2 < 2; ++m2) {
                const int mi = p * 2 + m2;
#pragma unroll
                for (int ni = 0; ni < 4; ++ni)
#pragma unroll
                    for (int r = 0; r < 4; ++r)
                        Fw[(m2 * 16 + cm + r) * 68 + ni * 16 + cn] = acc[mi][ni][r];
            }
#pragma unroll
            for (int it = 0; it < 8; ++it) {
                const int row = it * 4 + (lane >> 4);
                const int c4 = (lane & 15) * 4;
                f32x4 w = *(const f32x4*)&Fw[row * 68 + c4];
                const int gm = row0w + p * 32 + row;
                const float inv = __builtin_amdgcn_rcpf(lsum[bz * 2048 + gm]);
                w[0] *= inv; w[1] *= inv; w[2] *= inv; w[3] *= inv;
                *(f32x4*)&o3[bz * sC + (long)gm * N + col0w + c4] = w;
            }
        }
    } else if (MODE == 0 && (bn >> 2) == 2) {
        // ---- v projection: transposed [b,e,s]; 64e x 64s per wave ----
        const int ebase = (bn & 3) * 256 + wn * 64;
        float bb[4];
#pragma unroll
        for (int ni = 0; ni < 4; ++ni) bb[ni] = b2[ebase + ni * 16 + cn];
        const long bgi = row0w >> 11;
        const int sbase = row0w & 2047;
#pragma unroll
        for (int mi = 0; mi < 4; ++mi)
#pragma unroll
            for (int ni = 0; ni < 4; ++ni) {
                ushort4 pk;
                pk.x = f2bf(acc[mi][ni][0] + bb[ni]);
                pk.y = f2bf(acc[mi][ni][1] + bb[ni]);
                pk.z = f2bf(acc[mi][ni][2] + bb[ni]);
                pk.w = f2bf(acc[mi][ni][3] + bb[ni]);
                *(ushort4*)&Ew[(ni * 16 + cn) * 72 + mi * 16 + cm] = pk; // [e][s]
            }
#pragma unroll
        for (int it = 0; it < 8; ++it) {
            const int e = it * 8 + (lane >> 3);
            const int s8 = (lane & 7) * 8;
            const uint4 w = *(const uint4*)&Ew[e * 72 + s8];
            *(uint4*)&o2[(((bgi << 10) + ebase + e) << 11) + sbase + s8] = w;
        }
    } else if (MODE == 0) {
        // ---- q/k projection, row-major bf16; 64x64 per wave ----
        const int sec = bn >> 2;
        u16* C = sec ? o1 : o0;
        const float* bias = sec ? b1 : b0;
        const int ncol0 = (bn & 3) * 256 + wn * 64;
        float bb[4];
#pragma unroll
        for (int ni = 0; ni < 4; ++ni) bb[ni] = bias[ncol0 + ni * 16 + cn];
#pragma unroll
        for (int mi = 0; mi < 4; ++mi)
#pragma unroll
            for (int ni = 0; ni < 4; ++ni)
#pragma unroll
                for (int r = 0; r < 4; ++r)
                    Ew[(mi * 16 + cm + r) * 72 + ni * 16 + cn] = f2bf(acc[mi][ni][r] + bb[ni]);
#pragma unroll
        for (int it = 0; it < 8; ++it) {
            const int row = it * 8 + (lane >> 3);
            const int c8 = (lane & 7) * 8;
            const uint4 w = *(const uint4*)&Ew[row * 72 + c8];
            *(uint4*)&C[(long)(row0w + row) * 1024 + ncol0 + c8] = w;
        }
    } else {
        // ---- MODE 2: exp(s*scale), row-sum atomics, bf16 retile ----
#pragma unroll
        for (int mi = 0; mi < 4; ++mi)
#pragma unroll
            for (int ni = 0; ni < 4; ++ni)
#pragma unroll
                for (int r = 0; r < 4; ++r)
                    acc[mi][ni][r] = __expf(acc[mi][ni][r] * scale);
#pragma unroll
        for (int mi = 0; mi < 4; ++mi) {
#pragma unroll
            for (int r = 0; r < 4; ++r) {
                float sm = acc[mi][0][r] + acc[mi][1][r] + acc[mi][2][r] + acc[mi][3][r];
                sm += __shfl_xor(sm, 1);
                sm += __shfl_xor(sm, 2);
                sm += __shfl_xor(sm, 4);
                sm += __shfl_xor(sm, 8);
                if (cn == 0)
                    atomicAdd(&lsum[bz * 2048 + row0w + mi * 16 + cm + r], sm);
            }
        }
#pragma unroll
        for (int mi = 0; mi < 4; ++mi)
#pragma unroll
            for (int ni = 0; ni < 4; ++ni)
#pragma unroll
                for (int r = 0; r < 4; ++r)
                    Ew[(mi * 16 + cm + r) * 72 + ni * 16 + cn] = f2bf(acc[mi][ni][r]);
#pragma unroll
        for (int it = 0; it < 8; ++it) {
            const int row = it * 8 + (lane >> 3);
            const int c8 = (lane & 7) * 8;
            const uint4 w = *(const uint4*)&Ew[row * 72 + c8];
            *(uint4*)&o0[bz * sC + (long)(row0w + row) * N + col0w + c8] = w;
        }
    }
}

#undef GATHER
#undef PHASE

// fp32 -> bf16 converts + lsum zeroing.
__global__ __launch_bounds__(256) void cvt_all(
    const float* __restrict__ x, const float* __restrict__ wq,
    const float* __restrict__ wk, const float* __restrict__ wv,
    u16* __restrict__ xb, u16* __restrict__ wb, float* __restrict__ lsum)
{
    const int b = blockIdx.x;
    if (b >= 11264) {
        const long i = (long)(b - 11264) * 1024 + threadIdx.x * 4;
        *(f32x4*)(lsum + i) = (f32x4){0.f, 0.f, 0.f, 0.f};
        return;
    }
    const float* src; u16* dst; long base;
    if (b < 8192)       { src = x;  dst = xb;             base = (long)b * 1024; }
    else if (b < 9216)  { src = wq; dst = wb;             base = (long)(b - 8192) * 1024; }
    else if (b < 10240) { src = wk; dst = wb + (1 << 20); base = (long)(b - 9216) * 1024; }
    else                { src = wv; dst = wb + (2 << 20); base = (long)(b - 10240) * 1024; }
    const long i = base + threadIdx.x * 4;
    const f32x4 f = *(const f32x4*)(src + i);
    ushort4 o;
    o.x = f2bf(f[0]); o.y = f2bf(f[1]); o.z = f2bf(f[2]); o.w = f2bf(f[3]);
    *(ushort4*)(dst + i) = o;
}

extern "C" void kernel_launch(void* const* d_in, const int* in_sizes, int n_in,
                              void* d_out, int out_size, void* d_ws, size_t ws_size,
                              hipStream_t stream) {
    const float* x  = (const float*)d_in[0];
    const float* Wq = (const float*)d_in[1];
    const float* bq = (const float*)d_in[2];
    const float* Wk = (const float*)d_in[3];
    const float* bk = (const float*)d_in[4];
    const float* Wv = (const float*)d_in[5];
    const float* bv = (const float*)d_in[6];
    float* out = (float*)d_out;

    const int B = 4, S = 2048, D = 1024, E = 1024;
    const int M = B * S; // 8192
    const size_t LDS = 131072;

    u16* xb  = (u16*)d_ws;                       // [M,D]
    u16* wb  = xb  + (size_t)M * D;              // [3E,D]
    u16* qb  = wb  + (size_t)3 * E * D;          // [M,E]
    u16* kb  = qb  + (size_t)M * E;              // [M,E]
    u16* vbT = kb  + (size_t)M * E;              // [B,E,S]
    u16* sb  = vbT + (size_t)M * E;              // [B,S,S] exp-scores
    float* lsum = (float*)(sb + (size_t)M * S);  // [M]

    static bool attr_done = false;
    if (!attr_done) {
        (void)hipFuncSetAttribute((const void*)gemm8<0>, hipFuncAttributeMaxDynamicSharedMemorySize, (int)LDS);
        (void)hipFuncSetAttribute((const void*)gemm8<2>, hipFuncAttributeMaxDynamicSharedMemorySize, (int)LDS);
        (void)hipFuncSetAttribute((const void*)gemm8<3>, hipFuncAttributeMaxDynamicSharedMemorySize, (int)LDS);
        attr_done = true;
    }

    cvt_all<<<11272, 256, 0, stream>>>(x, Wq, Wk, Wv, xb, wb, lsum);

    dim3 blk(512);
    gemm8<0><<<768, blk, LDS, stream>>>(
        xb, wb, bq, bk, bv, qb, kb, vbT, nullptr, nullptr, M, 3 * E, D, 0, 0, 0, 1.f);
    gemm8<2><<<512, blk, LDS, stream>>>(
        qb, kb, nullptr, nullptr, nullptr, sb, nullptr, nullptr, nullptr, lsum,
        S, S, E, (long)S * E, (long)S * E, (long)S * S, 0.03125f);
    gemm8<3><<<256, blk, LDS, stream>>>(
        sb, vbT, nullptr, nullptr, nullptr, nullptr, nullptr, nullptr, out, lsum,
        S, E, S, (long)S * S, (long)E * S, (long)S * E, 1.f);
}

// Round 5
// 275.436 us; speedup vs baseline: 1.2944x; 1.2944x over previous
//
#include <hip/hip_runtime.h>
#include <stdint.h>

typedef unsigned short u16;
typedef __attribute__((ext_vector_type(8))) __bf16 bf16x8;
typedef __attribute__((ext_vector_type(4))) float f32x4;

__device__ __forceinline__ u16 f2bf(float f) {
    union { float f; uint32_t u; } v; v.f = f;
    uint32_t r = (v.u + 0x7FFFu + ((v.u >> 16) & 1u)) >> 16;
    return (u16)r;
}

__device__ __forceinline__ void lds_fence() {
    __asm__ volatile("s_waitcnt lgkmcnt(0)" ::: "memory");
}

#define BAR()   __asm__ volatile("s_barrier" ::: "memory")
#define VMW12() __asm__ volatile("s_waitcnt vmcnt(12)" ::: "memory")
#define VMW16() __asm__ volatile("s_waitcnt vmcnt(16)" ::: "memory")
#define VMW0()  __asm__ volatile("s_waitcnt vmcnt(0)" ::: "memory")

// ---------------------------------------------------------------------------
// ROUND 5: LDS-BW model (64 B/cy/CU; rounds 1-4 + m201 all consistent) says
// util cap = MFMA / LDS-bytes. 8 waves of 128x64 => 256 KB/Kt => 62% cap.
// FIX = FATTER WAVES: 256x256 tile, 4 waves (256 thr) 2Mx2N, 128x128/wave,
// acc[8][8]. LDS/Kt = 4x(128+128)x128B reads + 64KB writes = 192 KB => 83%
// cap. 1 wave/SIMD (launch_bounds(256,1) -> 512 VGPR budget; need ~420).
// One wave saturates the MFMA pipe (128 indep acc chains); ds_reads hide
// under 2483 cy MFMA/Kt; staging issued 2 Kt ahead (>> HBM latency).
// B restored to LDS staging (round-4 global-gather refuted: 16x VMEM segs).
//
// K-loop: 1 barrier per K-tile. Phase(buf,t+2) = { ds_read fa[8][2],fb[NJ][2]
// | 128 MFMA | stage all 16 chunks of tile t+2 into buf | vmcnt(16) | bar }.
// FIFO ledger: outstanding at wait = 32 (t+1:16 older, t+2:16 newer);
// vmcnt(16) retires exactly t+1 = what the next phase reads, issued a full
// phase (~3000 cy) earlier. WAR: stage(t+2)->buf is issued AFTER this
// phase's reads of buf; writes land >=200 cy after issue while reads
// complete in ~120 cy; cross-wave skew is barrier-bounded. Tail wraps mod NT
// (stale-safe); epilogue vmcnt(0)+bar before LDS reuse.
//
// LDS 128 KiB: 2 bufs x { A[2kb][256][32], B[2kb][BNR][32] } bf16.
// buf stride 32768 u16, B at +16384, A kb stride 8192, B kb stride BNR*32.
// Swizzle (T2, as rounds 1-3): element col ^= ((row&8)<<1), applied to the
// global SOURCE on staging (LDS dest linear for global_load_lds) and to the
// ds_read address.
//
// Grids (1 block/CU): m0 = 32bm x 12bn = 384 (1.5 rounds, tail accepted);
// m2 = 4z x 8bm x 8bn = 256 exact; m3 (BN=128) = 4z x 8bm x 8bn = 256 exact.
//
// MODE 0: fused QKV, N=3072. bn>>2: 0->q(o0,b0), 1->k(o1,b1), 2->v(b2)
//         transposed [b,e,s] into o2.
// MODE 2: exp(s*scale) bf16 into o0 + atomic row sums into lsum.
// MODE 3: fp32 out = acc / lsum[row] into o3 (tile 256x128).
// ---------------------------------------------------------------------------
template<int MODE>
__global__ __launch_bounds__(256, 1) void gemm4(
    const u16* __restrict__ A, const u16* __restrict__ Bt,
    const float* __restrict__ b0, const float* __restrict__ b1, const float* __restrict__ b2,
    u16* __restrict__ o0, u16* __restrict__ o1, u16* __restrict__ o2,
    float* __restrict__ o3, float* __restrict__ lsum,
    int M, int N, int K, long sA, long sB, long sC, float scale)
{
    extern __shared__ __align__(16) u16 smem[];
    constexpr int NJ  = (MODE == 3) ? 4 : 8;     // acc N frags per wave
    constexpr int BNR = (MODE == 3) ? 128 : 256; // B rows staged
    constexpr int BKB = BNR * 32;                // B kb stride (u16)
    constexpr int BC  = BNR / 64;                // B chunks per kb

    const int t = threadIdx.x;
    const int lane = t & 63;
    const int wave = t >> 6;
    const int wm = wave >> 1;   // 0..1
    const int wn = wave & 1;    // 0..1

    const int id = blockIdx.x;
    const int xcd = id & 7;
    const int s = id >> 3;
    int bm, bn;
    long bz;
    if (MODE == 0) {            // 384: s 0..47; XCD owns bm band [4k,4k+4)
        bm = xcd * 4 + (s & 3);     // 0..31
        bn = s >> 2;                // 0..11 (bn-major -> B strip L2 reuse)
        bz = 0;
    } else {                    // 256: s 0..31
        bz = xcd >> 1;
        bm = (xcd & 1) * 4 + (s & 3); // 0..7
        bn = s >> 2;                  // 0..7
    }
    const int row0 = bm * 256;
    const int col0 = bn * ((MODE == 3) ? 128 : 256);

    const u16* Ab = A + bz * sA;
    const u16* Bb = Bt + bz * sB;

    f32x4 acc[8][NJ];
#pragma unroll
    for (int i = 0; i < 8; ++i)
#pragma unroll
        for (int j = 0; j < NJ; ++j)
            acc[i][j] = (f32x4){0.f, 0.f, 0.f, 0.f};

    // ---- staging addressing (inverse-swizzled global source, linear dest) --
    const int trc = t >> 2;                              // 0..63 (row in chunk)
    const int gcol = ((t & 3) * 8) ^ ((trc & 8) << 1);   // swz within 32 cols
    const u16* aRow = Ab + (long)(row0 + trc) * K + gcol;
    const u16* bRow = Bb + (long)(col0 + trc) * K + gcol;

    // one global_load_lds instr: 64 rows x 32 cols of (isB, kb) chunk c
    auto stage1 = [&](int buf, int kt, int isB, int kb, int c) {
        const u16* g = (isB ? bRow : aRow) + (long)(c * 64) * K + kt * 64 + kb * 32;
        u16* d = smem + buf * 32768 + isB * 16384 + kb * (isB ? BKB : 8192)
               + c * 2048 + t * 8;
        __builtin_amdgcn_global_load_lds(
            (const __attribute__((address_space(1))) void*)g,
            (__attribute__((address_space(3))) void*)d, 16, 0, 0);
    };

#define STAGE_ALL(BUF, KT) do { \
    _Pragma("unroll") for (int kb = 0; kb < 2; ++kb) \
    _Pragma("unroll") for (int c = 0; c < 4; ++c) stage1(BUF, KT, 0, kb, c); \
    _Pragma("unroll") for (int kb = 0; kb < 2; ++kb) \
    _Pragma("unroll") for (int c = 0; c < BC; ++c) stage1(BUF, KT, 1, kb, c); \
} while (0)

    // ---- fragment read addressing (swizzled ds_read) ----
    const int fm = lane & 15;
    const int fk = (lane >> 4) * 8;
    const int fcol = fk ^ ((fm & 8) << 1);
    const int aB = (wm * 128 + fm) * 32 + fcol;          // + kh*8192 + mi*512
    const int bB = 16384 + (wn * (NJ * 16) + fm) * 32 + fcol; // + kh*BKB + ni*512

#define PHASE(BUF, KT2) do { \
    bf16x8 fa[8][2], fb[NJ][2]; \
    _Pragma("unroll") for (int mi = 0; mi < 8; ++mi) \
    _Pragma("unroll") for (int kh = 0; kh < 2; ++kh) \
        fa[mi][kh] = *(const bf16x8*)&smem[(BUF)*32768 + aB + kh*8192 + mi*512]; \
    _Pragma("unroll") for (int ni = 0; ni < NJ; ++ni) \
    _Pragma("unroll") for (int kh = 0; kh < 2; ++kh) \
        fb[ni][kh] = *(const bf16x8*)&smem[(BUF)*32768 + bB + kh*BKB + ni*512]; \
    __builtin_amdgcn_s_setprio(1); \
    _Pragma("unroll") for (int mi = 0; mi < 8; ++mi) \
    _Pragma("unroll") for (int ni = 0; ni < NJ; ++ni) \
    _Pragma("unroll") for (int kh = 0; kh < 2; ++kh) \
        acc[mi][ni] = __builtin_amdgcn_mfma_f32_16x16x32_bf16( \
            fa[mi][kh], fb[ni][kh], acc[mi][ni], 0, 0, 0); \
    __builtin_amdgcn_s_setprio(0); \
    STAGE_ALL(BUF, KT2); \
    if (MODE == 3) { VMW12(); } else { VMW16(); } \
    BAR(); \
} while (0)

    const int NT = K >> 6;
    const int NI = NT >> 1;

    // ---- prologue: tile0 -> buf0, tile1 -> buf1 ----
    STAGE_ALL(0, 0);
    STAGE_ALL(1, 1);
    if (MODE == 3) { VMW12(); } else { VMW16(); }
    BAR();

    for (int i = 0; i < NI; ++i) {
        int t2 = 2 * i + 2; if (t2 >= NT) t2 -= NT;
        int t3 = 2 * i + 3; if (t3 >= NT) t3 -= NT;
        PHASE(0, t2);
        PHASE(1, t3);
    }

    // ---- drain stale in-flight stagers before LDS reuse ----
    VMW0();
    BAR();

    // C/D layout: col = lane&15, row = (lane>>4)*4 + reg
    const int cm = (lane >> 4) * 4;
    const int cn = lane & 15;
    u16* Ew = smem + wave * 16384;     // 32 KiB per-wave window
    const int row0w = row0 + wm * 128;

    if constexpr (MODE == 3) {
        // ---- fp32 out (PV), /lsum[row]: 2 passes of 64 rows x 64 cols ----
        float* Fw = (float*)Ew;        // 64*68*4 = 17408 B <= 32768
        const int cnb3 = bn * 128 + wn * 64;
#pragma unroll
        for (int p = 0; p < 2; ++p) {
            if (p) lds_fence();
#pragma unroll
            for (int m4 = 0; m4 < 4; ++m4) {
                const int mi = p * 4 + m4;
#pragma unroll
                for (int ni = 0; ni < 4; ++ni)
#pragma unroll
                    for (int r = 0; r < 4; ++r)
                        Fw[(m4 * 16 + cm + r) * 68 + ni * 16 + cn] = acc[mi][ni][r];
            }
#pragma unroll
            for (int it = 0; it < 16; ++it) {
                const int row = it * 4 + (lane >> 4);
                const int c4 = (lane & 15) * 4;
                f32x4 w = *(const f32x4*)&Fw[row * 68 + c4];
                const int gm = row0w + p * 64 + row;
                const float inv = __builtin_amdgcn_rcpf(lsum[bz * 2048 + gm]);
                w[0] *= inv; w[1] *= inv; w[2] *= inv; w[3] *= inv;
                *(f32x4*)&o3[bz * sC + (long)gm * N + cnb3 + c4] = w;
            }
        }
    } else if (MODE == 0 && (bn >> 2) == 2) {
        // ---- v projection: transposed [b,e,s]; 2 e-passes of 64 ----
        const int ebase = (bn & 3) * 256 + wn * 128;
        float bb[8];
#pragma unroll
        for (int ni = 0; ni < 8; ++ni) bb[ni] = b2[ebase + ni * 16 + cn];
        const long bgi = row0w >> 11;
        const int sbase = row0w & 2047;
#pragma unroll
        for (int p = 0; p < 2; ++p) {
            if (p) lds_fence();
#pragma unroll
            for (int n4 = 0; n4 < 4; ++n4) {
                const int ni = p * 4 + n4;
#pragma unroll
                for (int mi = 0; mi < 8; ++mi) {
                    ushort4 pk;
                    pk.x = f2bf(acc[mi][ni][0] + bb[ni]);
                    pk.y = f2bf(acc[mi][ni][1] + bb[ni]);
                    pk.z = f2bf(acc[mi][ni][2] + bb[ni]);
                    pk.w = f2bf(acc[mi][ni][3] + bb[ni]);
                    *(ushort4*)&Ew[(n4 * 16 + cn) * 136 + mi * 16 + cm] = pk; // [e][s]
                }
            }
#pragma unroll
            for (int it = 0; it < 16; ++it) {
                const int e = it * 4 + (lane >> 4);
                const int s8 = (lane & 15) * 8;
                const uint4 w = *(const uint4*)&Ew[e * 136 + s8];
                *(uint4*)&o2[(((bgi << 10) + ebase + p * 64 + e) << 11) + sbase + s8] = w;
            }
        }
    } else if (MODE == 0) {
        // ---- q/k projection, row-major bf16; 2 row-passes of 64 ----
        const int sec = bn >> 2;
        u16* C = sec ? o1 : o0;
        const float* bias = sec ? b1 : b0;
        const int ncol0 = (bn & 3) * 256 + wn * 128;
        float bb[8];
#pragma unroll
        for (int ni = 0; ni < 8; ++ni) bb[ni] = bias[ncol0 + ni * 16 + cn];
#pragma unroll
        for (int p = 0; p < 2; ++p) {
            if (p) lds_fence();
#pragma unroll
            for (int m4 = 0; m4 < 4; ++m4) {
                const int mi = p * 4 + m4;
#pragma unroll
                for (int ni = 0; ni < 8; ++ni)
#pragma unroll
                    for (int r = 0; r < 4; ++r)
                        Ew[(m4 * 16 + cm + r) * 136 + ni * 16 + cn] = f2bf(acc[mi][ni][r] + bb[ni]);
            }
#pragma unroll
            for (int it = 0; it < 16; ++it) {
                const int row = it * 4 + (lane >> 4);
                const int c8 = (lane & 15) * 8;
                const uint4 w = *(const uint4*)&Ew[row * 136 + c8];
                *(uint4*)&C[(long)(row0w + p * 64 + row) * 1024 + ncol0 + c8] = w;
            }
        }
    } else {
        // ---- MODE 2: exp(s*scale), row-sum atomics, bf16 retile ----
        const int col0w = bn * 256 + wn * 128;
#pragma unroll
        for (int mi = 0; mi < 8; ++mi)
#pragma unroll
            for (int ni = 0; ni < 8; ++ni)
#pragma unroll
                for (int r = 0; r < 4; ++r)
                    acc[mi][ni][r] = __expf(acc[mi][ni][r] * scale);
#pragma unroll
        for (int mi = 0; mi < 8; ++mi) {
#pragma unroll
            for (int r = 0; r < 4; ++r) {
                float sm = acc[mi][0][r] + acc[mi][1][r] + acc[mi][2][r] + acc[mi][3][r]
                         + acc[mi][4][r] + acc[mi][5][r] + acc[mi][6][r] + acc[mi][7][r];
                sm += __shfl_xor(sm, 1);
                sm += __shfl_xor(sm, 2);
                sm += __shfl_xor(sm, 4);
                sm += __shfl_xor(sm, 8);
                if (cn == 0)
                    atomicAdd(&lsum[bz * 2048 + row0w + mi * 16 + cm + r], sm);
            }
        }
#pragma unroll
        for (int p = 0; p < 2; ++p) {
            if (p) lds_fence();
#pragma unroll
            for (int m4 = 0; m4 < 4; ++m4) {
                const int mi = p * 4 + m4;
#pragma unroll
                for (int ni = 0; ni < 8; ++ni)
#pragma unroll
                    for (int r = 0; r < 4; ++r)
                        Ew[(m4 * 16 + cm + r) * 136 + ni * 16 + cn] = f2bf(acc[mi][ni][r]);
            }
#pragma unroll
            for (int it = 0; it < 16; ++it) {
                const int row = it * 4 + (lane >> 4);
                const int c8 = (lane & 15) * 8;
                const uint4 w = *(const uint4*)&Ew[row * 136 + c8];
                *(uint4*)&o0[bz * sC + (long)(row0w + p * 64 + row) * N + col0w + c8] = w;
            }
        }
    }
}

#undef STAGE_ALL
#undef PHASE

// fp32 -> bf16 converts + lsum zeroing.
__global__ __launch_bounds__(256) void cvt_all(
    const float* __restrict__ x, const float* __restrict__ wq,
    const float* __restrict__ wk, const float* __restrict__ wv,
    u16* __restrict__ xb, u16* __restrict__ wb, float* __restrict__ lsum)
{
    const int b = blockIdx.x;
    if (b >= 11264) {
        const long i = (long)(b - 11264) * 1024 + threadIdx.x * 4;
        *(f32x4*)(lsum + i) = (f32x4){0.f, 0.f, 0.f, 0.f};
        return;
    }
    const float* src; u16* dst; long base;
    if (b < 8192)       { src = x;  dst = xb;             base = (long)b * 1024; }
    else if (b < 9216)  { src = wq; dst = wb;             base = (long)(b - 8192) * 1024; }
    else if (b < 10240) { src = wk; dst = wb + (1 << 20); base = (long)(b - 9216) * 1024; }
    else                { src = wv; dst = wb + (2 << 20); base = (long)(b - 10240) * 1024; }
    const long i = base + threadIdx.x * 4;
    const f32x4 f = *(const f32x4*)(src + i);
    ushort4 o;
    o.x = f2bf(f[0]); o.y = f2bf(f[1]); o.z = f2bf(f[2]); o.w = f2bf(f[3]);
    *(ushort4*)(dst + i) = o;
}

extern "C" void kernel_launch(void* const* d_in, const int* in_sizes, int n_in,
                              void* d_out, int out_size, void* d_ws, size_t ws_size,
                              hipStream_t stream) {
    const float* x  = (const float*)d_in[0];
    const float* Wq = (const float*)d_in[1];
    const float* bq = (const float*)d_in[2];
    const float* Wk = (const float*)d_in[3];
    const float* bk = (const float*)d_in[4];
    const float* Wv = (const float*)d_in[5];
    const float* bv = (const float*)d_in[6];
    float* out = (float*)d_out;

    const int B = 4, S = 2048, D = 1024, E = 1024;
    const int M = B * S; // 8192
    const size_t LDS = 131072;

    u16* xb  = (u16*)d_ws;                       // [M,D]
    u16* wb  = xb  + (size_t)M * D;              // [3E,D]
    u16* qb  = wb  + (size_t)3 * E * D;          // [M,E]
    u16* kb  = qb  + (size_t)M * E;              // [M,E]
    u16* vbT = kb  + (size_t)M * E;              // [B,E,S]
    u16* sb  = vbT + (size_t)M * E;              // [B,S,S] exp-scores
    float* lsum = (float*)(sb + (size_t)M * S);  // [M]

    static bool attr_done = false;
    if (!attr_done) {
        (void)hipFuncSetAttribute((const void*)gemm4<0>, hipFuncAttributeMaxDynamicSharedMemorySize, (int)LDS);
        (void)hipFuncSetAttribute((const void*)gemm4<2>, hipFuncAttributeMaxDynamicSharedMemorySize, (int)LDS);
        (void)hipFuncSetAttribute((const void*)gemm4<3>, hipFuncAttributeMaxDynamicSharedMemorySize, (int)LDS);
        attr_done = true;
    }

    cvt_all<<<11272, 256, 0, stream>>>(x, Wq, Wk, Wv, xb, wb, lsum);

    dim3 blk(256);
    gemm4<0><<<384, blk, LDS, stream>>>(
        xb, wb, bq, bk, bv, qb, kb, vbT, nullptr, nullptr, M, 3 * E, D, 0, 0, 0, 1.f);
    gemm4<2><<<256, blk, LDS, stream>>>(
        qb, kb, nullptr, nullptr, nullptr, sb, nullptr, nullptr, nullptr, lsum,
        S, S, E, (long)S * E, (long)S * E, (long)S * S, 0.03125f);
    gemm4<3><<<256, blk, LDS, stream>>>(
        sb, vbT, nullptr, nullptr, nullptr, nullptr, nullptr, nullptr, out, lsum,
        S, E, S, (long)S * S, (long)E * S, (long)S * E, 1.f);
}

// Round 6
// 236.642 us; speedup vs baseline: 1.5065x; 1.1639x over previous
//
#include <hip/hip_runtime.h>
#include <stdint.h>

typedef unsigned short u16;
typedef __attribute__((ext_vector_type(8))) __bf16 bf16x8;
typedef __attribute__((ext_vector_type(4))) float f32x4;

__device__ __forceinline__ u16 f2bf(float f) {
    union { float f; uint32_t u; } v; v.f = f;
    uint32_t r = (v.u + 0x7FFFu + ((v.u >> 16) & 1u)) >> 16;
    return (u16)r;
}

// Wave-local LDS drain (WAR protection when a window is rewritten).
__device__ __forceinline__ void lds_fence() {
    __asm__ volatile("s_waitcnt lgkmcnt(0)" ::: "memory");
}

#define BM 128
#define BN 128
#define BK 64   // staged as two [128][32] halves (round-7 structure, best measured)

// C = A * Bt^T, A [M,K] bf16 rm, Bt [N,K] bf16 rm. K % 64 == 0.
// ROUND 6: full revert to the proven baseline structure (2-barrier K-loop,
// static 36 KB LDS, 4 blocks/CU resident) — rounds 1-5 established that on
// this K=1024 shape the high-TLP 128-tile structure beats every deeper
// 256-tile pipeline (tails + short-K pro/epilogue eat the schedule gains).
// ONE change vs baseline: MODE 3 re-tiled 128x128 -> 64x128 so its grid goes
// 512 (2 blocks/CU, the only under-occupied dispatch, 29% util) -> 1024
// (4 blocks/CU, matching m0/m2 residency).
// MODE 0: fused QKV projection, N=3072, grid 1536. Section bn>>10: 0->q(b0,o0),
//         1->k(b1,o1), 2->v(b2) TRANSPOSED [b,e,s] into o2.
// MODE 2: exp(s*scale) bf16 into o0 + atomic row sums into lsum. grid 1024.
// MODE 3: fp32 out = acc / lsum[row] into o3. grid 1024 (tile 64x128,
//         4 waves 1M x 4N, per-wave 64x32, acc[4][2], single-pass epilogue).
template<int MODE>
__global__ __launch_bounds__(256, 4) void gemm_bt(
    const u16* __restrict__ A, const u16* __restrict__ Bt,
    const float* __restrict__ b0, const float* __restrict__ b1, const float* __restrict__ b2,
    u16* __restrict__ o0, u16* __restrict__ o1, u16* __restrict__ o2,
    float* __restrict__ o3, float* __restrict__ lsum,
    int M, int N, int K, long sA, long sB, long sC, float scale)
{
    __shared__ __align__(16) u16 smem[4 * 64 * 72]; // 36864 B
    // staging: A half0 @0, A half1 @4096, B half0 @8192, B half1 @12288 (u16 idx)

    constexpr int NJ = (MODE == 3) ? 2 : 4;   // per-wave N frags
    constexpr int AR = (MODE == 3) ? 1 : 2;   // A 64-row staging groups

    const int t = threadIdx.x;
    const int lane = t & 63;
    const int wave = t >> 6;
    const int wm = (MODE == 3) ? 0 : (wave & 1) * 64;
    const int wn = (MODE == 3) ? wave * 32 : (wave >> 1) * 64;

    // ---- XCD-aware block swizzle ----
    const int id = blockIdx.x;
    const int xcd = id & 7;
    const int s = id >> 3;
    int bm, bn;
    long bz;
    if (MODE == 0) {        // 1536 blocks: 24 bn x 64 bm; XCD k -> bm band [8k, 8k+8)
        bn = (s >> 3) * BN;
        bm = (xcd * 8 + (s & 7)) * BM;
        bz = 0;
    } else if (MODE == 2) { // 1024 blocks: 16 bn x 16 bm x 4 z; XCD -> (z, bm half)
        bz = xcd >> 1;
        bn = (s & 15) * BN;
        bm = ((xcd & 1) * 8 + (s >> 4)) * BM;
    } else {                // 1024 blocks: 8 bn x 32 bm(64) x 4 z; XCD -> (z, bm half)
        bz = xcd >> 1;
        bn = (s & 7) * BN;
        bm = ((xcd & 1) * 16 + (s >> 3)) * 64;
    }

    const u16* Ab = A + bz * sA;
    const u16* Bb = Bt + bz * sB;

    f32x4 acc[4][NJ];
#pragma unroll
    for (int i = 0; i < 4; ++i)
#pragma unroll
        for (int j = 0; j < NJ; ++j)
            acc[i][j] = (f32x4){0.f, 0.f, 0.f, 0.f};

    const int lrow = t >> 2;          // 0..63
    const int lcol = (t & 3) * 8;     // 0,8,16,24 within a 32-col half
    const int fm = lane & 15;
    const int fk = (lane >> 4) * 8;

    for (int k0 = 0; k0 < K; k0 += BK) {
#pragma unroll
        for (int h = 0; h < 2; ++h)
#pragma unroll
            for (int r = 0; r < AR; ++r) {
                const u16* ga = Ab + (long)(bm + r * 64 + lrow) * K + (k0 + h * 32 + lcol);
                __builtin_amdgcn_global_load_lds(
                    (const __attribute__((address_space(1))) void*)ga,
                    (__attribute__((address_space(3))) void*)&smem[h * 4096 + (r * 256 + t) * 8],
                    16, 0, 0);
            }
#pragma unroll
        for (int h = 0; h < 2; ++h)
#pragma unroll
            for (int r = 0; r < 2; ++r) {
                const u16* gb = Bb + (long)(bn + r * 64 + lrow) * K + (k0 + h * 32 + lcol);
                __builtin_amdgcn_global_load_lds(
                    (const __attribute__((address_space(1))) void*)gb,
                    (__attribute__((address_space(3))) void*)&smem[8192 + h * 4096 + (r * 256 + t) * 8],
                    16, 0, 0);
            }
        __syncthreads();

#pragma unroll
        for (int h = 0; h < 2; ++h) {
            bf16x8 af[4], bfr[NJ];
#pragma unroll
            for (int i = 0; i < 4; ++i)
                af[i]  = *(const bf16x8*)&smem[h * 4096 + (wm + i * 16 + fm) * 32 + fk];
#pragma unroll
            for (int i = 0; i < NJ; ++i)
                bfr[i] = *(const bf16x8*)&smem[8192 + h * 4096 + (wn + i * 16 + fm) * 32 + fk];
#pragma unroll
            for (int i = 0; i < 4; ++i)
#pragma unroll
                for (int j = 0; j < NJ; ++j)
                    acc[i][j] = __builtin_amdgcn_mfma_f32_16x16x32_bf16(af[i], bfr[j], acc[i][j], 0, 0, 0);
        }
        __syncthreads();
    }

    // C/D layout: col = lane&15, row = (lane>>4)*4 + reg
    const int cm = (lane >> 4) * 4;
    const int cn = lane & 15;
    u16* Ew = smem + wave * 4608; // 9216 B per-wave window

    if (MODE == 3) {
        // ---- fp32 out (PV), /lsum[row]: single pass, 64 rows x 32 cols ----
        float* Fw = (float*)Ew; // 64*36*4 = 9216 B exactly
#pragma unroll
        for (int i = 0; i < 4; ++i)
#pragma unroll
            for (int j = 0; j < 2; ++j)
#pragma unroll
                for (int r = 0; r < 4; ++r)
                    Fw[(i * 16 + cm + r) * 36 + j * 16 + cn] = acc[i][j][r];
#pragma unroll
        for (int it = 0; it < 8; ++it) {
            const int row = it * 8 + (lane >> 3);
            const int c4 = (lane & 7) * 4;
            f32x4 w = *(const f32x4*)&Fw[row * 36 + c4];
            const int gm = bm + row;
            const float inv = __builtin_amdgcn_rcpf(lsum[bz * 2048 + gm]);
            w[0] *= inv; w[1] *= inv; w[2] *= inv; w[3] *= inv;
            *(f32x4*)&o3[bz * sC + (long)gm * N + bn + wn + c4] = w;
        }
    } else if (MODE == 0 && (bn >> 10) == 2) {
        // ---- v projection: transposed [b,e,s]; single-shot ----
        float bb[4];
#pragma unroll
        for (int j = 0; j < 4; ++j) bb[j] = b2[(bn & 1023) + wn + j * 16 + cn];
        const int bgi = (bm + wm) >> 11;
        const int sbase = (bm + wm) & 2047;
#pragma unroll
        for (int i = 0; i < 4; ++i)
#pragma unroll
            for (int j = 0; j < 4; ++j) {
                ushort4 pk;
                pk.x = f2bf(acc[i][j][0] + bb[j]);
                pk.y = f2bf(acc[i][j][1] + bb[j]);
                pk.z = f2bf(acc[i][j][2] + bb[j]);
                pk.w = f2bf(acc[i][j][3] + bb[j]);
                *(ushort4*)&Ew[(j * 16 + cn) * 72 + i * 16 + cm] = pk; // [e][s]
            }
#pragma unroll
        for (int it = 0; it < 8; ++it) {
            const int e = it * 8 + (lane >> 3);
            const int s8 = (lane & 7) * 8;
            const uint4 w = *(const uint4*)&Ew[e * 72 + s8];
            const int eg = (bn & 1023) + wn + e;
            *(uint4*)&o2[((((long)bgi << 10) + eg) << 11) + sbase + s8] = w;
        }
    } else if (MODE == 0) {
        // ---- q/k projection, row-major bf16, single-shot ----
        const int sec = bn >> 10;
        u16* C = sec ? o1 : o0;
        const float* bias = sec ? b1 : b0;
        const int ncol0 = bn & 1023;
        float bb[4];
#pragma unroll
        for (int j = 0; j < 4; ++j) bb[j] = bias[ncol0 + wn + j * 16 + cn];
#pragma unroll
        for (int i = 0; i < 4; ++i)
#pragma unroll
            for (int j = 0; j < 4; ++j) {
                const int col = j * 16 + cn;
#pragma unroll
                for (int r = 0; r < 4; ++r)
                    Ew[(i * 16 + cm + r) * 72 + col] = f2bf(acc[i][j][r] + bb[j]);
            }
#pragma unroll
        for (int it = 0; it < 8; ++it) {
            const int row = it * 8 + (lane >> 3);
            const int c8 = (lane & 7) * 8;
            const uint4 w = *(const uint4*)&Ew[row * 72 + c8];
            const int gm = bm + wm + row;
            *(uint4*)&C[(long)gm * 1024 + ncol0 + wn + c8] = w;
        }
    } else {
        // ---- MODE 2: exp(s*scale), row-sum atomics, single-shot bf16 retile ----
#pragma unroll
        for (int i = 0; i < 4; ++i)
#pragma unroll
            for (int j = 0; j < 4; ++j)
#pragma unroll
                for (int r = 0; r < 4; ++r)
                    acc[i][j][r] = __expf(acc[i][j][r] * scale);
#pragma unroll
        for (int i = 0; i < 4; ++i) {
#pragma unroll
            for (int r = 0; r < 4; ++r) {
                float sm = acc[i][0][r] + acc[i][1][r] + acc[i][2][r] + acc[i][3][r];
                sm += __shfl_xor(sm, 1);
                sm += __shfl_xor(sm, 2);
                sm += __shfl_xor(sm, 4);
                sm += __shfl_xor(sm, 8);
                if (cn == 0)
                    atomicAdd(&lsum[bz * 2048 + bm + wm + i * 16 + cm + r], sm);
            }
        }
#pragma unroll
        for (int i = 0; i < 4; ++i)
#pragma unroll
            for (int j = 0; j < 4; ++j) {
                const int col = j * 16 + cn;
#pragma unroll
                for (int r = 0; r < 4; ++r)
                    Ew[(i * 16 + cm + r) * 72 + col] = f2bf(acc[i][j][r]);
            }
#pragma unroll
        for (int it = 0; it < 8; ++it) {
            const int row = it * 8 + (lane >> 3);
            const int c8 = (lane & 7) * 8;
            const uint4 w = *(const uint4*)&Ew[row * 72 + c8];
            const int gm = bm + wm + row;
            *(uint4*)&o0[bz * sC + (long)gm * N + bn + wn + c8] = w;
        }
    }
}

// fp32 -> bf16 converts + lsum zeroing.
__global__ __launch_bounds__(256) void cvt_all(
    const float* __restrict__ x, const float* __restrict__ wq,
    const float* __restrict__ wk, const float* __restrict__ wv,
    u16* __restrict__ xb, u16* __restrict__ wb, float* __restrict__ lsum)
{
    const int b = blockIdx.x;
    if (b >= 11264) {
        const long i = (long)(b - 11264) * 1024 + threadIdx.x * 4;
        *(f32x4*)(lsum + i) = (f32x4){0.f, 0.f, 0.f, 0.f};
        return;
    }
    const float* src; u16* dst; long base;
    if (b < 8192)       { src = x;  dst = xb;             base = (long)b * 1024; }
    else if (b < 9216)  { src = wq; dst = wb;             base = (long)(b - 8192) * 1024; }
    else if (b < 10240) { src = wk; dst = wb + (1 << 20); base = (long)(b - 9216) * 1024; }
    else                { src = wv; dst = wb + (2 << 20); base = (long)(b - 10240) * 1024; }
    const long i = base + threadIdx.x * 4;
    const f32x4 f = *(const f32x4*)(src + i);
    ushort4 o;
    o.x = f2bf(f[0]); o.y = f2bf(f[1]); o.z = f2bf(f[2]); o.w = f2bf(f[3]);
    *(ushort4*)(dst + i) = o;
}

extern "C" void kernel_launch(void* const* d_in, const int* in_sizes, int n_in,
                              void* d_out, int out_size, void* d_ws, size_t ws_size,
                              hipStream_t stream) {
    const float* x  = (const float*)d_in[0];
    const float* Wq = (const float*)d_in[1];
    const float* bq = (const float*)d_in[2];
    const float* Wk = (const float*)d_in[3];
    const float* bk = (const float*)d_in[4];
    const float* Wv = (const float*)d_in[5];
    const float* bv = (const float*)d_in[6];
    float* out = (float*)d_out;

    const int B = 4, S = 2048, D = 1024, E = 1024;
    const int M = B * S; // 8192

    u16* xb  = (u16*)d_ws;                       // [M,D]
    u16* wb  = xb  + (size_t)M * D;              // [3E,D]
    u16* qb  = wb  + (size_t)3 * E * D;          // [M,E]
    u16* kb  = qb  + (size_t)M * E;              // [M,E]
    u16* vbT = kb  + (size_t)M * E;              // [B,E,S]
    u16* sb  = vbT + (size_t)M * E;              // [B,S,S] exp-scores
    float* lsum = (float*)(sb + (size_t)M * S);  // [M]

    cvt_all<<<11272, 256, 0, stream>>>(x, Wq, Wk, Wv, xb, wb, lsum);

    dim3 blk(256);
    gemm_bt<0><<<1536, blk, 0, stream>>>(
        xb, wb, bq, bk, bv, qb, kb, vbT, nullptr, nullptr, M, 3 * E, D, 0, 0, 0, 1.f);
    gemm_bt<2><<<1024, blk, 0, stream>>>(
        qb, kb, nullptr, nullptr, nullptr, sb, nullptr, nullptr, nullptr, lsum,
        S, S, E, (long)S * E, (long)S * E, (long)S * S, 0.03125f);
    gemm_bt<3><<<1024, blk, 0, stream>>>(
        sb, vbT, nullptr, nullptr, nullptr, nullptr, nullptr, nullptr, out, lsum,
        S, E, S, (long)S * S, (long)E * S, (long)S * E, 1.f);
}